// Round 13
// baseline (7035.600 us; speedup 1.0000x reference)
//
#include <hip/hip_runtime.h>
#include <hip/hip_bf16.h>
#include <hip/hip_fp16.h>

#define NN 50000
#define EE 1600000
#define GG 500

#define NB 1024          // persistent grid: 256 CUs x 4 blocks/CU (co-resident)
#define GX1 196          // gemm row-blocks = ceil(NN/256)
#define GB1 (GX1 * 5)    // gemm1 tiles
#define CVB 240          // cvt_w tiles
#define NBV 196          // scan tiles = ceil(NN/256)
#define PT  3125         // prop tiles (16 nodes each)

typedef __bf16 bf16x8 __attribute__((ext_vector_type(8)));
typedef float  f32x4  __attribute__((ext_vector_type(4)));

__device__ __forceinline__ float b2f(ushort u) {
  return __uint_as_float(((unsigned)u) << 16);
}
__device__ __forceinline__ ushort f2b(float f) {
  unsigned u = __float_as_uint(f);
  unsigned r = (u + 0x7fff + ((u >> 16) & 1)) >> 16;   // RNE
  return (ushort)r;
}
__device__ __forceinline__ float lo16(uint v) { return __uint_as_float(v << 16); }
__device__ __forceinline__ float hi16(uint v) { return __uint_as_float(v & 0xffff0000u); }
__device__ __forceinline__ float h2f(uint hb) {
  __half h; ushort s = (ushort)hb;
  __builtin_memcpy(&h, &s, 2);
  return __half2float(h);
}

// Device-scope soft barrier. ALL threads fence (drains each wave's outstanding
// stores/atomics), then thread 0 arrives and spins on the memory-side counter.
// Correct only because all NB blocks are co-resident.
__device__ __forceinline__ void gsync(int* bar, int ph) {
  __threadfence();
  __syncthreads();
  if (threadIdx.x == 0) {
    __hip_atomic_fetch_add(bar, 1, __ATOMIC_RELEASE, __HIP_MEMORY_SCOPE_AGENT);
    while (__hip_atomic_load(bar, __ATOMIC_ACQUIRE, __HIP_MEMORY_SCOPE_AGENT) < ph * NB)
      __builtin_amdgcn_s_sleep(1);
  }
  __syncthreads();
}

// ---- prop phase (V5b): 4 node-chains/wave, 4B edge meta {src:u16|fp16 w} ----
template<int NADD, bool RELUB>
__device__ __forceinline__ void prop_phase(
    const int* __restrict__ rowptr, const uint* __restrict__ edges,
    const ushort* __restrict__ g, int sg,
    const ushort* __restrict__ a1, int sa1, float c1,
    const ushort* __restrict__ a2, int sa2, float c2,
    const float* __restrict__ bias,
    ushort* __restrict__ out, int so, float alpha)
{
  const int wave = threadIdx.x >> 6;
  const int lane = threadIdx.x & 63;
  const int q    = lane >> 4;
  const int grp  = (lane >> 3) & 1;
  const int sub  = lane & 7;
  for (int vt = blockIdx.x; vt < PT; vt += NB) {
    const int nd = (vt * 4 + wave) * 4 + q;
    const int e0 = rowptr[nd];
    const int e1 = rowptr[nd + 1];
    float ra[8] = {}, rb[8] = {};
    int j = e0 + grp;
    for (; j + 2 < e1; j += 4) {
      uint p0 = edges[j];
      uint p1 = edges[j + 2];
      uint4 v0 = *(const uint4*)&g[(size_t)(p0 & 0xffffu) * sg + sub * 8];
      uint4 v1 = *(const uint4*)&g[(size_t)(p1 & 0xffffu) * sg + sub * 8];
      float w0 = h2f(p0 >> 16);
      float w1 = h2f(p1 >> 16);
      ra[0] += w0 * lo16(v0.x); ra[1] += w0 * hi16(v0.x);
      ra[2] += w0 * lo16(v0.y); ra[3] += w0 * hi16(v0.y);
      ra[4] += w0 * lo16(v0.z); ra[5] += w0 * hi16(v0.z);
      ra[6] += w0 * lo16(v0.w); ra[7] += w0 * hi16(v0.w);
      rb[0] += w1 * lo16(v1.x); rb[1] += w1 * hi16(v1.x);
      rb[2] += w1 * lo16(v1.y); rb[3] += w1 * hi16(v1.y);
      rb[4] += w1 * lo16(v1.z); rb[5] += w1 * hi16(v1.z);
      rb[6] += w1 * lo16(v1.w); rb[7] += w1 * hi16(v1.w);
    }
    float r[8];
    #pragma unroll
    for (int e = 0; e < 8; ++e) {
      float t = ra[e] + rb[e];
      t += __shfl_xor(t, 8, 64);
      r[e] = alpha * t;
    }
    if constexpr (NADD >= 1) {
      uint4 u = *(const uint4*)&a1[(size_t)nd * sa1 + sub * 8];
      r[0] += c1 * lo16(u.x); r[1] += c1 * hi16(u.x);
      r[2] += c1 * lo16(u.y); r[3] += c1 * hi16(u.y);
      r[4] += c1 * lo16(u.z); r[5] += c1 * hi16(u.z);
      r[6] += c1 * lo16(u.w); r[7] += c1 * hi16(u.w);
    }
    if constexpr (NADD >= 2) {
      uint4 u = *(const uint4*)&a2[(size_t)nd * sa2 + sub * 8];
      r[0] += c2 * lo16(u.x); r[1] += c2 * hi16(u.x);
      r[2] += c2 * lo16(u.y); r[3] += c2 * hi16(u.y);
      r[4] += c2 * lo16(u.z); r[5] += c2 * hi16(u.z);
      r[6] += c2 * lo16(u.w); r[7] += c2 * hi16(u.w);
    }
    if constexpr (RELUB) {
      float4 b0 = *(const float4*)&bias[sub * 8];
      float4 b1 = *(const float4*)&bias[sub * 8 + 4];
      r[0] = fmaxf(r[0] + b0.x, 0.f); r[1] = fmaxf(r[1] + b0.y, 0.f);
      r[2] = fmaxf(r[2] + b0.z, 0.f); r[3] = fmaxf(r[3] + b0.w, 0.f);
      r[4] = fmaxf(r[4] + b1.x, 0.f); r[5] = fmaxf(r[5] + b1.y, 0.f);
      r[6] = fmaxf(r[6] + b1.z, 0.f); r[7] = fmaxf(r[7] + b1.w, 0.f);
    }
    if (grp == 0) {
      uint4 o;
      o.x = (uint)f2b(r[0]) | ((uint)f2b(r[1]) << 16);
      o.y = (uint)f2b(r[2]) | ((uint)f2b(r[3]) << 16);
      o.z = (uint)f2b(r[4]) | ((uint)f2b(r[5]) << 16);
      o.w = (uint)f2b(r[6]) | ((uint)f2b(r[7]) << 16);
      *(uint4*)&out[(size_t)nd * so + sub * 8] = o;
    }
  }
}

// ---- gemm phase (bf16 in/out, B^T weights from L2) ----
template<int Ci, int Co, bool BR>
__device__ __forceinline__ void gemm_phase(const ushort* __restrict__ A,
    const ushort* __restrict__ Wt, const float* __restrict__ bias,
    ushort* __restrict__ C, int ntiles)
{
  const int lane = threadIdx.x & 63;
  const int wid  = threadIdx.x >> 6;
  const int lr = lane & 15;
  const int lk = (lane >> 4) << 3;
  for (int vt = blockIdx.x; vt < ntiles; vt += NB) {
    const int rb = (vt % GX1) * 256;
    const int cb = (vt / GX1) * 64;
    f32x4 acc[4][4] = {};
    for (int kc = 0; kc < Ci; kc += 64) {
      bf16x8 bfrag[2][4];
      #pragma unroll
      for (int ks = 0; ks < 2; ++ks)
        #pragma unroll
        for (int nt = 0; nt < 4; ++nt)
          bfrag[ks][nt] = *(const bf16x8*)&Wt[(size_t)(cb + nt * 16 + lr) * Ci + kc + ks * 32 + lk];
      #pragma unroll
      for (int s = 0; s < 4; ++s) {
        const int row = rb + (wid * 4 + s) * 16 + lr;
        const ushort* ap = &A[(size_t)row * Ci + kc + lk];
        #pragma unroll
        for (int ks = 0; ks < 2; ++ks) {
          bf16x8 af = {};
          if (row < NN) af = *(const bf16x8*)(ap + ks * 32);
          #pragma unroll
          for (int nt = 0; nt < 4; ++nt)
            acc[s][nt] = __builtin_amdgcn_mfma_f32_16x16x32_bf16(af, bfrag[ks][nt], acc[s][nt], 0, 0, 0);
        }
      }
    }
    #pragma unroll
    for (int s = 0; s < 4; ++s)
      #pragma unroll
      for (int nt = 0; nt < 4; ++nt) {
        const int col = cb + nt * 16 + lr;
        #pragma unroll
        for (int r = 0; r < 4; ++r) {
          const int row = rb + (wid * 4 + s) * 16 + ((lane >> 4) << 2) + r;
          if (row < NN) {
            float v = acc[s][nt][r];
            if constexpr (BR) v = fmaxf(v + bias[col], 0.f);
            C[(size_t)row * Co + col] = f2b(v);
          }
        }
      }
  }
}

// ================= the persistent pipeline kernel =================

__global__ __launch_bounds__(256, 4) void megaAll(
    const int* __restrict__ src, const int* __restrict__ dst,
    const float* __restrict__ ea, const int* __restrict__ batch,
    const float* __restrict__ x, const float* __restrict__ W1,
    const float* __restrict__ W2, const float* __restrict__ W3,
    const float* __restrict__ lb1, const float* __restrict__ lb2,
    const float* __restrict__ lb3, const float* __restrict__ Wl,
    const float* __restrict__ bl,
    float* __restrict__ deg, int* __restrict__ cnt, int* __restrict__ rank,
    int* __restrict__ rowptr, int* __restrict__ bsum,
    uint* __restrict__ edges, ushort* __restrict__ Acat, ushort* __restrict__ Bcat,
    ushort* __restrict__ h1, ushort* __restrict__ Wt2, ushort* __restrict__ Wt3,
    int* __restrict__ partial, float* __restrict__ pooled, float* __restrict__ gcnt,
    float* __restrict__ outp, int* __restrict__ bar)
{
  __shared__ int sbuf[256];
  const int tid  = threadIdx.x;
  const int lane = tid & 63;
  const int wave = tid >> 6;
  int ph = 0;

  // ---- phase 0: hist ∪ gemm1 ∪ cvt_w (5:1 striped virtual tiles) ----
  for (int vt = blockIdx.x; vt < 7500; vt += NB) {
    const int r = vt % 6, gq = vt / 6;
    if (r < 5) {
      int i = (gq * 5 + r) * 256 + tid;
      if (i < EE) {
        atomicAdd(&deg[src[i]], ea[i]);
        rank[i] = atomicAdd(&cnt[dst[i]], 1);
      }
    } else if (gq < GB1) {
      const int bx = gq % GX1, by = gq / GX1;
      const int rb = bx * 256, cb = by * 64;
      const int lr = lane & 15, lk = (lane >> 4) << 3;
      f32x4 acc[4][4] = {};
      for (int kc = 0; kc < 128; kc += 64) {
        bf16x8 bfrag[2][4];
        #pragma unroll
        for (int ks = 0; ks < 2; ++ks)
          #pragma unroll
          for (int nt = 0; nt < 4; ++nt) {
            int col = cb + nt * 16 + lr;
            int kk  = kc + ks * 32 + lk;
            const float* wp = &W1[((size_t)(col >> 6) * 128 + kk) * 64 + (col & 63)];
            union { bf16x8 v; ushort u[8]; } bu;
            #pragma unroll
            for (int t = 0; t < 8; ++t) bu.u[t] = f2b(wp[t * 64]);
            bfrag[ks][nt] = bu.v;
          }
        #pragma unroll
        for (int s = 0; s < 4; ++s) {
          const int row = rb + (wave * 4 + s) * 16 + lr;
          #pragma unroll
          for (int ks = 0; ks < 2; ++ks) {
            union { bf16x8 v; ushort u[8]; } au;
            if (row < NN) {
              const float* ap = &x[(size_t)row * 128 + kc + ks * 32 + lk];
              float4 f0 = *(const float4*)ap;
              float4 f1 = *(const float4*)(ap + 4);
              au.u[0] = f2b(f0.x); au.u[1] = f2b(f0.y);
              au.u[2] = f2b(f0.z); au.u[3] = f2b(f0.w);
              au.u[4] = f2b(f1.x); au.u[5] = f2b(f1.y);
              au.u[6] = f2b(f1.z); au.u[7] = f2b(f1.w);
            } else {
              au.v = bf16x8{};
            }
            #pragma unroll
            for (int nt = 0; nt < 4; ++nt)
              acc[s][nt] = __builtin_amdgcn_mfma_f32_16x16x32_bf16(au.v, bfrag[ks][nt],
                                                                   acc[s][nt], 0, 0, 0);
          }
        }
      }
      #pragma unroll
      for (int s = 0; s < 4; ++s)
        #pragma unroll
        for (int nt = 0; nt < 4; ++nt) {
          const int col = cb + nt * 16 + lr;
          #pragma unroll
          for (int rr = 0; rr < 4; ++rr) {
            const int row = rb + (wave * 4 + s) * 16 + ((lane >> 4) << 2) + rr;
            if (row < NN) Acat[(size_t)row * 320 + col] = f2b(acc[s][nt][rr]);
          }
        }
    } else if (gq < GB1 + CVB) {
      int t = (gq - GB1) * 256 + tid;
      if (t < 320 * 64) {
        int j = t / 64, k = t % 64;
        Wt2[t] = f2b(W2[((size_t)(j >> 6) * 64 + k) * 64 + (j & 63)]);
      } else {
        int t2 = t - 320 * 64;
        int j = t2 / 320, k = t2 % 320;
        Wt3[t2] = f2b(W3[(size_t)k * 128 + j]);
      }
    }
  }
  gsync(bar, ++ph);

  // ---- phase 1: dinv + padded-count block scan ----
  for (int vt = blockIdx.x; vt < NBV; vt += NB) {
    int i = vt * 256 + tid;
    if (i < NN) { float d = deg[i]; deg[i] = (d > 0.f) ? (1.0f / sqrtf(d)) : 0.f; }
    int v = (i < NN) ? ((cnt[i] + 3) & ~3) : 0;
    sbuf[tid] = v; __syncthreads();
    for (int off = 1; off < 256; off <<= 1) {
      int xv = (tid >= off) ? sbuf[tid - off] : 0;
      __syncthreads(); sbuf[tid] += xv; __syncthreads();
    }
    if (i < NN) partial[i] = sbuf[tid];
    if (tid == 255) bsum[vt] = sbuf[255];
    __syncthreads();
  }
  gsync(bar, ++ph);

  // ---- phase 2: rowptr (absorbs scan2 via LDS reduce of bsum) + pad ----
  for (int vt = blockIdx.x; vt < NBV; vt += NB) {
    sbuf[tid] = (tid < vt) ? bsum[tid] : 0;
    __syncthreads();
    for (int off = 128; off > 0; off >>= 1) {
      if (tid < off) sbuf[tid] += sbuf[tid + off];
      __syncthreads();
    }
    const int off0 = sbuf[0];
    int i = vt * 256 + tid;
    if (i < NN) {
      int end = partial[i] + off0;
      rowptr[i + 1] = end;
      if (i == 0) rowptr[0] = 0;
      int c = cnt[i];
      int start = end - ((c + 3) & ~3);
      for (int qq = start + c; qq < end; ++qq) edges[qq] = 0u;
    }
    __syncthreads();
  }
  gsync(bar, ++ph);

  // ---- phase 3: atomic-free scatter ----
  for (int vt = blockIdx.x; vt < 6250; vt += NB) {
    int i = vt * 256 + tid;
    if (i < EE) {
      int s = src[i], d = dst[i];
      float w = -deg[s] * ea[i] * deg[d];     // deg holds dinv now
      __half h = __float2half_rn(w);
      ushort hb; __builtin_memcpy(&hb, &h, 2);
      edges[rowptr[d] + rank[i]] = (uint)(unsigned short)s | ((uint)hb << 16);
    }
  }
  gsync(bar, ++ph);

  ushort* A0 = Acat + 0 * 64;  ushort* A1 = Acat + 1 * 64;  ushort* A2 = Acat + 2 * 64;
  ushort* A3 = Acat + 3 * 64;  ushort* A4 = Acat + 4 * 64;
  ushort* B0 = Bcat + 0 * 64;  ushort* B1 = Bcat + 1 * 64;  ushort* B2 = Bcat + 2 * 64;
  ushort* B3 = Bcat + 3 * 64;  ushort* B4 = Bcat + 4 * 64;
  ushort* h3 = Bcat;
  const int S = 320;

  // ---- Layer 1 Clenshaw ----
  prop_phase<1, false>(rowptr, edges, A4, S, A3, S, 1.f, nullptr, 0, 0.f, nullptr, A3, S, 2.f);
  gsync(bar, ++ph);
  prop_phase<2, false>(rowptr, edges, A3, S, A2, S, 1.f, A4, S, -1.f, nullptr, A2, S, 2.f);
  gsync(bar, ++ph);
  prop_phase<2, false>(rowptr, edges, A2, S, A1, S, 1.f, A3, S, -1.f, nullptr, A1, S, 2.f);
  gsync(bar, ++ph);
  prop_phase<2, true>(rowptr, edges, A1, S, A0, S, 1.f, A2, S, -1.f, lb1, h1, 64, 1.f);
  gsync(bar, ++ph);

  // ---- Layer 2: gemm2 then Clenshaw ----
  gemm_phase<64, 320, false>(h1, Wt2, nullptr, Bcat, GX1 * 5);
  gsync(bar, ++ph);
  prop_phase<1, false>(rowptr, edges, B4, S, B3, S, 1.f, nullptr, 0, 0.f, nullptr, B3, S, 2.f);
  gsync(bar, ++ph);
  prop_phase<2, false>(rowptr, edges, B3, S, B2, S, 1.f, B4, S, -1.f, nullptr, B2, S, 2.f);
  gsync(bar, ++ph);
  prop_phase<2, false>(rowptr, edges, B2, S, B1, S, 1.f, B3, S, -1.f, nullptr, B1, S, 2.f);
  gsync(bar, ++ph);
  prop_phase<2, true>(rowptr, edges, B1, S, B0, S, 1.f, B2, S, -1.f, lb2, A0, S, 1.f);
  gsync(bar, ++ph);

  // ---- Layer 3: forward recursion ----
  prop_phase<0, false>(rowptr, edges, A0, S, nullptr, 0, 0.f, nullptr, 0, 0.f, nullptr, A1, S, 1.f);
  gsync(bar, ++ph);
  prop_phase<1, false>(rowptr, edges, A1, S, A0, S, -1.f, nullptr, 0, 0.f, nullptr, A2, S, 2.f);
  gsync(bar, ++ph);
  prop_phase<1, false>(rowptr, edges, A2, S, A1, S, -1.f, nullptr, 0, 0.f, nullptr, A3, S, 2.f);
  gsync(bar, ++ph);
  prop_phase<1, false>(rowptr, edges, A3, S, A2, S, -1.f, nullptr, 0, 0.f, nullptr, A4, S, 2.f);
  gsync(bar, ++ph);
  gemm_phase<320, 128, true>(Acat, Wt3, lb3, h3, GX1 * 2);
  gsync(bar, ++ph);

  // ---- pool (half-block = 64-node tile) ----
  for (int vt = blockIdx.x * 2 + (tid >> 7); vt < 782; vt += 2 * NB) {
    const int f = tid & 127;
    const int i0 = vt * 64;
    const int iend = min(i0 + 64, NN);
    int cur = batch[i0];
    float acc = 0.f;
    int run = 0;
    for (int i = i0; i < iend; ++i) {
      int b = batch[i];
      float v = b2f(h3[(size_t)i * 128 + f]);
      if (b != cur) {
        atomicAdd(&pooled[cur * 128 + f], acc);
        if (f == 0) atomicAdd(&gcnt[cur], (float)run);
        acc = 0.f; run = 0; cur = b;
      }
      acc += v; run++;
    }
    atomicAdd(&pooled[cur * 128 + f], acc);
    if (f == 0) atomicAdd(&gcnt[cur], (float)run);
  }
  gsync(bar, ++ph);

  // ---- head: one wave per graph ----
  for (int g = blockIdx.x * 4 + wave; g < GG; g += NB * 4) {
    float denom = fmaxf(gcnt[g], 1.f);
    float p0 = pooled[g * 128 + lane] / denom;
    float p1 = pooled[g * 128 + 64 + lane] / denom;
    float a = p0 * Wl[lane * 2 + 0] + p1 * Wl[(lane + 64) * 2 + 0];
    float b = p0 * Wl[lane * 2 + 1] + p1 * Wl[(lane + 64) * 2 + 1];
    #pragma unroll
    for (int off = 32; off > 0; off >>= 1) {
      a += __shfl_xor(a, off, 64);
      b += __shfl_xor(b, off, 64);
    }
    if (lane == 0) {
      a += bl[0]; b += bl[1];
      float m = fmaxf(a, b);
      float z = logf(expf(a - m) + expf(b - m)) + m;
      outp[g * 2 + 0] = a - z;
      outp[g * 2 + 1] = b - z;
    }
  }
}

// ---------------- launch ----------------

extern "C" void kernel_launch(void* const* d_in, const int* in_sizes, int n_in,
                              void* d_out, int out_size, void* d_ws, size_t ws_size,
                              hipStream_t stream) {
  const float* x   = (const float*)d_in[0];
  const int*   ei  = (const int*)d_in[1];
  const float* ea  = (const float*)d_in[2];
  const int* batch = (const int*)d_in[3];
  const float* W1  = (const float*)d_in[4];
  const float* lb1 = (const float*)d_in[5];
  const float* W2  = (const float*)d_in[6];
  const float* lb2 = (const float*)d_in[7];
  const float* W3  = (const float*)d_in[8];
  const float* lb3 = (const float*)d_in[9];
  const float* Wl  = (const float*)d_in[10];
  const float* bl  = (const float*)d_in[11];
  const int* srcv = ei;
  const int* dstv = ei + EE;

  char* w = (char*)d_ws;
  auto alloc = [&](size_t bytes) -> char* {
    char* p = w; w += (bytes + 255) & ~(size_t)255; return p;
  };
  // zero-init region: deg, cnt, pooled+gcnt, bar (one memset)
  float* deg    = (float*)alloc((size_t)NN * 4);          // becomes dinv in phase 1
  int*   cnt    = (int*)alloc((size_t)NN * 4);
  float* pooled = (float*)alloc((size_t)(GG * 128 + GG) * 4);
  float* gcnt   = pooled + GG * 128;
  int*   bar    = (int*)alloc(256 * 4);
  char*  zero_end = w;
  int*   rowptr = (int*)alloc((size_t)(NN + 1) * 4);
  int*   bsum   = (int*)alloc(256 * 4);
  int*   rank   = (int*)alloc((size_t)EE * 4);
  uint*  edges  = (uint*)alloc((size_t)(EE + 4 * NN) * 4); // rows padded to %4
  ushort* Acat  = (ushort*)alloc((size_t)NN * 320 * 2);
  ushort* Bcat  = (ushort*)alloc((size_t)NN * 320 * 2);
  ushort* h1    = (ushort*)alloc((size_t)NN * 64 * 2);
  ushort* Wt2   = (ushort*)alloc((size_t)320 * 64 * 2);
  ushort* Wt3   = (ushort*)alloc((size_t)128 * 320 * 2);
  int*   partial = (int*)Bcat;     // scan scratch (Bcat unused until gemm2)

  hipMemsetAsync(deg, 0, (size_t)(zero_end - (char*)deg), stream);

  megaAll<<<NB, 256, 0, stream>>>(srcv, dstv, ea, batch, x, W1, W2, W3,
                                  lb1, lb2, lb3, Wl, bl,
                                  deg, cnt, rank, rowptr, bsum, edges,
                                  Acat, Bcat, h1, Wt2, Wt3, partial,
                                  pooled, gcnt, (float*)d_out, bar);
}

// Round 14
// 592.302 us; speedup vs baseline: 11.8784x; 11.8784x over previous
//
#include <hip/hip_runtime.h>
#include <hip/hip_bf16.h>
#include <hip/hip_fp16.h>

#define NN 50000
#define EE 1600000
#define GG 500

#define GX1 196          // gemm row-blocks = ceil(NN/256)
#define GB1 (GX1 * 5)    // gemm1 blocks (5 column tiles of 64)
#define CVB 240          // cvt_w blocks (61440 elems / 256)
// mega1: 7500 blocks in 1250 groups of 6 -> 5 hist + 1 rider

typedef __bf16 bf16x8 __attribute__((ext_vector_type(8)));
typedef float  f32x4  __attribute__((ext_vector_type(4)));

__device__ __forceinline__ float b2f(ushort u) {
  return __uint_as_float(((unsigned)u) << 16);
}
__device__ __forceinline__ ushort f2b(float f) {
  unsigned u = __float_as_uint(f);
  unsigned r = (u + 0x7fff + ((u >> 16) & 1)) >> 16;   // RNE
  return (ushort)r;
}
__device__ __forceinline__ float lo16(uint v) { return __uint_as_float(v << 16); }
__device__ __forceinline__ float hi16(uint v) { return __uint_as_float(v & 0xffff0000u); }
__device__ __forceinline__ float h2f(uint hb) {
  __half h; ushort s = (ushort)hb;
  __builtin_memcpy(&h, &s, 2);
  return __half2float(h);
}

// Edge meta: one u32 per edge = {src:u16 | fp16(w):u16}.

// ---------------- mega phase 1: hist ∪ gemm1 ∪ cvt_w, role-STRIPED ----------------

__global__ __launch_bounds__(256) void mega1(
    const int* __restrict__ src, const int* __restrict__ dst,
    const float* __restrict__ ea, float* __restrict__ deg,
    int* __restrict__ cnt, int* __restrict__ rank,
    const float* __restrict__ x, const float* __restrict__ W1,
    ushort* __restrict__ Acat,
    const float* __restrict__ W2, const float* __restrict__ W3,
    ushort* __restrict__ Wt2, ushort* __restrict__ Wt3)
{
  const int r = blockIdx.x % 6;
  const int gq = blockIdx.x / 6;      // 0..1249
  if (r < 5) {
    int i = (gq * 5 + r) * 256 + threadIdx.x;
    if (i < EE) {
      atomicAdd(&deg[src[i]], ea[i]);
      rank[i] = atomicAdd(&cnt[dst[i]], 1);
    }
    return;
  }
  if (gq < GB1) {
    const int bx = gq % GX1, by = gq / GX1;
    const int lane = threadIdx.x & 63;
    const int wid  = threadIdx.x >> 6;
    const int rb = bx * 256;
    const int cb = by * 64;
    const int lr = lane & 15;
    const int lk = (lane >> 4) << 3;
    f32x4 acc[4][4] = {};
    for (int kc = 0; kc < 128; kc += 64) {
      bf16x8 bfrag[2][4];
      #pragma unroll
      for (int ks = 0; ks < 2; ++ks)
        #pragma unroll
        for (int nt = 0; nt < 4; ++nt) {
          int col = cb + nt * 16 + lr;        // 0..319
          int kk  = kc + ks * 32 + lk;
          const float* wp = &W1[((size_t)(col >> 6) * 128 + kk) * 64 + (col & 63)];
          union { bf16x8 v; ushort u[8]; } bu;
          #pragma unroll
          for (int t = 0; t < 8; ++t) bu.u[t] = f2b(wp[t * 64]);
          bfrag[ks][nt] = bu.v;
        }
      #pragma unroll
      for (int s = 0; s < 4; ++s) {
        const int row = rb + (wid * 4 + s) * 16 + lr;
        #pragma unroll
        for (int ks = 0; ks < 2; ++ks) {
          union { bf16x8 v; ushort u[8]; } au;
          if (row < NN) {
            const float* ap = &x[(size_t)row * 128 + kc + ks * 32 + lk];
            float4 f0 = *(const float4*)ap;
            float4 f1 = *(const float4*)(ap + 4);
            au.u[0] = f2b(f0.x); au.u[1] = f2b(f0.y);
            au.u[2] = f2b(f0.z); au.u[3] = f2b(f0.w);
            au.u[4] = f2b(f1.x); au.u[5] = f2b(f1.y);
            au.u[6] = f2b(f1.z); au.u[7] = f2b(f1.w);
          } else {
            au.v = bf16x8{};
          }
          #pragma unroll
          for (int nt = 0; nt < 4; ++nt)
            acc[s][nt] = __builtin_amdgcn_mfma_f32_16x16x32_bf16(au.v, bfrag[ks][nt],
                                                                 acc[s][nt], 0, 0, 0);
        }
      }
    }
    #pragma unroll
    for (int s = 0; s < 4; ++s)
      #pragma unroll
      for (int nt = 0; nt < 4; ++nt) {
        const int col = cb + nt * 16 + lr;
        #pragma unroll
        for (int rr = 0; rr < 4; ++rr) {
          const int row = rb + (wid * 4 + s) * 16 + ((lane >> 4) << 2) + rr;
          if (row < NN) Acat[(size_t)row * 320 + col] = f2b(acc[s][nt][rr]);
        }
      }
    return;
  }
  if (gq < GB1 + CVB) {
    int t = (gq - GB1) * 256 + threadIdx.x;      // 0..61439
    if (t < 320 * 64) {
      int j = t / 64, k = t % 64;
      Wt2[t] = f2b(W2[((size_t)(j >> 6) * 64 + k) * 64 + (j & 63)]);
    } else {
      int t2 = t - 320 * 64;            // < 128*320
      int j = t2 / 320, k = t2 % 320;
      Wt3[t2] = f2b(W3[(size_t)k * 128 + j]);
    }
  }
}

// ---------------- scans (8-padded counts) + fused dinv / pad ----------------

__global__ void scan1(const int* __restrict__ cnt, float* __restrict__ deg,
                      int* __restrict__ partial, int* __restrict__ bsum, int n) {
  __shared__ int s[256];
  int t = threadIdx.x, i = blockIdx.x * 256 + t;
  if (i < n) { float d = deg[i]; deg[i] = (d > 0.f) ? (1.0f / sqrtf(d)) : 0.f; }
  int v = (i < n) ? ((cnt[i] + 7) & ~7) : 0;
  s[t] = v; __syncthreads();
  for (int off = 1; off < 256; off <<= 1) {
    int xv = (t >= off) ? s[t - off] : 0;
    __syncthreads(); s[t] += xv; __syncthreads();
  }
  if (i < n) partial[i] = s[t];
  if (t == 255) bsum[blockIdx.x] = s[255];
}

// scan3 absorbs scan2: each block reduces bsum[0..blockIdx-1] in LDS.
__global__ void scan3(const int* __restrict__ partial, const int* __restrict__ bsum,
                      const int* __restrict__ cnt, int* __restrict__ rowptr,
                      uint* __restrict__ edges, int n) {
  __shared__ int soff[256];
  int t = threadIdx.x;
  soff[t] = (t < (int)blockIdx.x) ? bsum[t] : 0;   // blockIdx < 196 <= 256
  __syncthreads();
  for (int off = 128; off > 0; off >>= 1) {
    if (t < off) soff[t] += soff[t + off];
    __syncthreads();
  }
  const int off0 = soff[0];
  int i = blockIdx.x * 256 + t;
  if (i < n) {
    int end = partial[i] + off0;          // padded end of row i
    rowptr[i + 1] = end;
    if (i == 0) rowptr[0] = 0;
    int c = cnt[i];
    int start = end - ((c + 7) & ~7);
    for (int q = start + c; q < end; ++q) edges[q] = 0u;  // {src=0, w=+0.0h}
  }
}

// atomic-free scatter: pos = rowptr[d] + rank; meta packed {src:u16 | fp16 w}
__global__ void scatter_kernel(const int* __restrict__ src, const int* __restrict__ dst,
                               const float* __restrict__ ea, const float* __restrict__ dinv,
                               const int* __restrict__ rowptr, const int* __restrict__ rank,
                               uint* __restrict__ edges, int e) {
  int i = blockIdx.x * blockDim.x + threadIdx.x;
  if (i < e) {
    int s = src[i], d = dst[i];
    float w = -dinv[s] * ea[i] * dinv[d];
    __half h = __float2half_rn(w);
    ushort hb; __builtin_memcpy(&hb, &h, 2);
    edges[rowptr[d] + rank[i]] = (uint)(unsigned short)s | ((uint)hb << 16);
  }
}

// ---------------- sparse propagation V5c: 4 node-chains/wave, unroll x4 ------
// Wave = 4 nodes (quarter each): q=lane>>4 node, grp=(lane>>3)&1 edge slot,
// sub=lane&7 the 16B row chunk. Rows padded to %8 -> per-chain stream (stride
// 2) is an exact multiple of 4: inner loop issues 4 independent gathers per
// chain per iteration = 16 outstanding gathers per wave (was 8).
// out = alpha * prop(g) + c1*a1 + c2*a2   [+ bias, relu]

template<int NADD, bool RELUB>
__global__ __launch_bounds__(256) void prop_kernel(
    const int* __restrict__ rowptr, const uint* __restrict__ edges,
    const ushort* __restrict__ g, int sg,
    const ushort* __restrict__ a1, int sa1, float c1,
    const ushort* __restrict__ a2, int sa2, float c2,
    const float* __restrict__ bias,
    ushort* __restrict__ out, int so, int n, float alpha)
{
  const int wave = threadIdx.x >> 6;
  const int lane = threadIdx.x & 63;
  const int q    = lane >> 4;        // node chain 0..3
  const int grp  = (lane >> 3) & 1;  // edge slot within pair
  const int sub  = lane & 7;         // 16B chunk of 128B row
  const int nd = (blockIdx.x * 4 + wave) * 4 + q;   // grid covers n exactly
  const int e0 = rowptr[nd];
  const int e1 = rowptr[nd + 1];     // (e1-e0) % 8 == 0

  float ra[8] = {}, rb[8] = {}, rc[8] = {}, rd[8] = {};
  int j = e0 + grp;                  // this lane's edge stream: stride 2
  for (; j + 6 < e1; j += 8) {       // 4 edges/chain/iter, no tail (rows %8)
    uint p0 = edges[j];
    uint p1 = edges[j + 2];
    uint p2 = edges[j + 4];
    uint p3 = edges[j + 6];
    uint4 v0 = *(const uint4*)&g[(size_t)(p0 & 0xffffu) * sg + sub * 8];
    uint4 v1 = *(const uint4*)&g[(size_t)(p1 & 0xffffu) * sg + sub * 8];
    uint4 v2 = *(const uint4*)&g[(size_t)(p2 & 0xffffu) * sg + sub * 8];
    uint4 v3 = *(const uint4*)&g[(size_t)(p3 & 0xffffu) * sg + sub * 8];
    float w0 = h2f(p0 >> 16);
    float w1 = h2f(p1 >> 16);
    float w2 = h2f(p2 >> 16);
    float w3 = h2f(p3 >> 16);
    ra[0] += w0 * lo16(v0.x); ra[1] += w0 * hi16(v0.x);
    ra[2] += w0 * lo16(v0.y); ra[3] += w0 * hi16(v0.y);
    ra[4] += w0 * lo16(v0.z); ra[5] += w0 * hi16(v0.z);
    ra[6] += w0 * lo16(v0.w); ra[7] += w0 * hi16(v0.w);
    rb[0] += w1 * lo16(v1.x); rb[1] += w1 * hi16(v1.x);
    rb[2] += w1 * lo16(v1.y); rb[3] += w1 * hi16(v1.y);
    rb[4] += w1 * lo16(v1.z); rb[5] += w1 * hi16(v1.z);
    rb[6] += w1 * lo16(v1.w); rb[7] += w1 * hi16(v1.w);
    rc[0] += w2 * lo16(v2.x); rc[1] += w2 * hi16(v2.x);
    rc[2] += w2 * lo16(v2.y); rc[3] += w2 * hi16(v2.y);
    rc[4] += w2 * lo16(v2.z); rc[5] += w2 * hi16(v2.z);
    rc[6] += w2 * lo16(v2.w); rc[7] += w2 * hi16(v2.w);
    rd[0] += w3 * lo16(v3.x); rd[1] += w3 * hi16(v3.x);
    rd[2] += w3 * lo16(v3.y); rd[3] += w3 * hi16(v3.y);
    rd[4] += w3 * lo16(v3.z); rd[5] += w3 * hi16(v3.z);
    rd[6] += w3 * lo16(v3.w); rd[7] += w3 * hi16(v3.w);
  }
  float r[8];
  #pragma unroll
  for (int e = 0; e < 8; ++e) {
    float t = (ra[e] + rb[e]) + (rc[e] + rd[e]);
    t += __shfl_xor(t, 8, 64);       // combine the two edge slots (within quarter)
    r[e] = alpha * t;
  }
  if constexpr (NADD >= 1) {
    uint4 u = *(const uint4*)&a1[(size_t)nd * sa1 + sub * 8];
    r[0] += c1 * lo16(u.x); r[1] += c1 * hi16(u.x);
    r[2] += c1 * lo16(u.y); r[3] += c1 * hi16(u.y);
    r[4] += c1 * lo16(u.z); r[5] += c1 * hi16(u.z);
    r[6] += c1 * lo16(u.w); r[7] += c1 * hi16(u.w);
  }
  if constexpr (NADD >= 2) {
    uint4 u = *(const uint4*)&a2[(size_t)nd * sa2 + sub * 8];
    r[0] += c2 * lo16(u.x); r[1] += c2 * hi16(u.x);
    r[2] += c2 * lo16(u.y); r[3] += c2 * hi16(u.y);
    r[4] += c2 * lo16(u.z); r[5] += c2 * hi16(u.z);
    r[6] += c2 * lo16(u.w); r[7] += c2 * hi16(u.w);
  }
  if constexpr (RELUB) {
    float4 b0 = *(const float4*)&bias[sub * 8];
    float4 b1 = *(const float4*)&bias[sub * 8 + 4];
    r[0] = fmaxf(r[0] + b0.x, 0.f); r[1] = fmaxf(r[1] + b0.y, 0.f);
    r[2] = fmaxf(r[2] + b0.z, 0.f); r[3] = fmaxf(r[3] + b0.w, 0.f);
    r[4] = fmaxf(r[4] + b1.x, 0.f); r[5] = fmaxf(r[5] + b1.y, 0.f);
    r[6] = fmaxf(r[6] + b1.z, 0.f); r[7] = fmaxf(r[7] + b1.w, 0.f);
  }
  if (grp == 0) {                    // 8 lanes per quarter write the 128B row
    uint4 o;
    o.x = (uint)f2b(r[0]) | ((uint)f2b(r[1]) << 16);
    o.y = (uint)f2b(r[2]) | ((uint)f2b(r[3]) << 16);
    o.z = (uint)f2b(r[4]) | ((uint)f2b(r[5]) << 16);
    o.w = (uint)f2b(r[6]) | ((uint)f2b(r[7]) << 16);
    *(uint4*)&out[(size_t)nd * so + sub * 8] = o;
  }
}

// ---------------- MFMA GEMM (bf16 in, bf16 out) ----------------

template<int Ci, int Co, bool BR>
__global__ __launch_bounds__(256) void gemm_mfma(const ushort* __restrict__ A,
    const ushort* __restrict__ Wt, const float* __restrict__ bias,
    ushort* __restrict__ C, int n)
{
  const int lane = threadIdx.x & 63;
  const int wid  = threadIdx.x >> 6;
  const int rb = blockIdx.x * 256;
  const int cb = blockIdx.y * 64;
  const int lr = lane & 15;
  const int lk = (lane >> 4) << 3;
  f32x4 acc[4][4] = {};

  for (int kc = 0; kc < Ci; kc += 64) {
    bf16x8 bfrag[2][4];
    #pragma unroll
    for (int ks = 0; ks < 2; ++ks)
      #pragma unroll
      for (int nt = 0; nt < 4; ++nt)
        bfrag[ks][nt] = *(const bf16x8*)&Wt[(size_t)(cb + nt * 16 + lr) * Ci + kc + ks * 32 + lk];
    #pragma unroll
    for (int s = 0; s < 4; ++s) {
      const int row = rb + (wid * 4 + s) * 16 + lr;
      const ushort* ap = &A[(size_t)row * Ci + kc + lk];
      #pragma unroll
      for (int ks = 0; ks < 2; ++ks) {
        bf16x8 af = {};
        if (row < n) af = *(const bf16x8*)(ap + ks * 32);
        #pragma unroll
        for (int nt = 0; nt < 4; ++nt)
          acc[s][nt] = __builtin_amdgcn_mfma_f32_16x16x32_bf16(af, bfrag[ks][nt], acc[s][nt], 0, 0, 0);
      }
    }
  }

  #pragma unroll
  for (int s = 0; s < 4; ++s)
    #pragma unroll
    for (int nt = 0; nt < 4; ++nt) {
      const int col = cb + nt * 16 + lr;
      #pragma unroll
      for (int r = 0; r < 4; ++r) {
        const int row = rb + (wid * 4 + s) * 16 + ((lane >> 4) << 2) + r;
        if (row < n) {
          float v = acc[s][nt][r];
          if constexpr (BR) v = fmaxf(v + bias[col], 0.f);
          C[(size_t)row * Co + col] = f2b(v);
        }
      }
    }
}

// ---------------- pooling + head ----------------

__global__ __launch_bounds__(128) void pool_kernel(const ushort* __restrict__ h,
    const int* __restrict__ batch, float* __restrict__ pooled,
    float* __restrict__ gcnt, int n) {
  const int f = threadIdx.x;
  const int i0 = blockIdx.x * 64;
  const int iend = min(i0 + 64, n);
  int cur = batch[i0];
  float acc = 0.f;
  int run = 0;
  for (int i = i0; i < iend; ++i) {
    int b = batch[i];
    float v = b2f(h[(size_t)i * 128 + f]);
    if (b != cur) {
      atomicAdd(&pooled[cur * 128 + f], acc);
      if (f == 0) atomicAdd(&gcnt[cur], (float)run);
      acc = 0.f; run = 0; cur = b;
    }
    acc += v; run++;
  }
  atomicAdd(&pooled[cur * 128 + f], acc);
  if (f == 0) atomicAdd(&gcnt[cur], (float)run);
}

__global__ __launch_bounds__(128) void head_kernel(const float* __restrict__ pooled,
    const float* __restrict__ gcnt, const float* __restrict__ Wl,
    const float* __restrict__ bl, float* __restrict__ outp)
{
  int g = blockIdx.x, t = threadIdx.x;
  float denom = fmaxf(gcnt[g], 1.f);
  float p = pooled[g * 128 + t] / denom;
  __shared__ float s0[128], s1[128];
  s0[t] = p * Wl[t * 2 + 0];
  s1[t] = p * Wl[t * 2 + 1];
  __syncthreads();
  for (int off = 64; off > 0; off >>= 1) {
    if (t < off) { s0[t] += s0[t + off]; s1[t] += s1[t + off]; }
    __syncthreads();
  }
  if (t == 0) {
    float a = s0[0] + bl[0], b = s1[0] + bl[1];
    float m = fmaxf(a, b);
    float z = logf(expf(a - m) + expf(b - m)) + m;
    outp[g * 2 + 0] = a - z;
    outp[g * 2 + 1] = b - z;
  }
}

// ---------------- launch ----------------

extern "C" void kernel_launch(void* const* d_in, const int* in_sizes, int n_in,
                              void* d_out, int out_size, void* d_ws, size_t ws_size,
                              hipStream_t stream) {
  const float* x   = (const float*)d_in[0];
  const int*   ei  = (const int*)d_in[1];
  const float* ea  = (const float*)d_in[2];
  const int* batch = (const int*)d_in[3];
  const float* W1  = (const float*)d_in[4];
  const float* lb1 = (const float*)d_in[5];
  const float* W2  = (const float*)d_in[6];
  const float* lb2 = (const float*)d_in[7];
  const float* W3  = (const float*)d_in[8];
  const float* lb3 = (const float*)d_in[9];
  const float* Wl  = (const float*)d_in[10];
  const float* bl  = (const float*)d_in[11];
  const int* srcv = ei;
  const int* dstv = ei + EE;

  char* w = (char*)d_ws;
  auto alloc = [&](size_t bytes) -> char* {
    char* p = w; w += (bytes + 255) & ~(size_t)255; return p;
  };
  // zero-init region: deg, cnt, pooled+gcnt contiguous (one memset)
  float* deg    = (float*)alloc((size_t)NN * 4);          // becomes dinv in scan1
  int*   cnt    = (int*)alloc((size_t)NN * 4);
  float* pooled = (float*)alloc((size_t)(GG * 128 + GG) * 4);
  float* gcnt   = pooled + GG * 128;
  char*  zero_end = w;
  int*   rowptr = (int*)alloc((size_t)(NN + 1) * 4);
  int*   bsum   = (int*)alloc(256 * 4);
  int*   rank   = (int*)alloc((size_t)EE * 4);
  uint*  edges  = (uint*)alloc((size_t)(EE + 8 * NN) * 4); // rows padded to %8
  ushort* Acat  = (ushort*)alloc((size_t)NN * 320 * 2);   // a_k / Clenshaw / Tx_k
  ushort* Bcat  = (ushort*)alloc((size_t)NN * 320 * 2);   // layer2 blocks; later h3
  ushort* h1    = (ushort*)alloc((size_t)NN * 64 * 2);
  ushort* Wt2   = (ushort*)alloc((size_t)320 * 64 * 2);
  ushort* Wt3   = (ushort*)alloc((size_t)128 * 320 * 2);
  int*   partial = (int*)Bcat;     // scan scratch (Bcat unused until gemm2)
  ushort* h3 = Bcat;               // layer-3 output reuses Bcat

  hipMemsetAsync(deg, 0, (size_t)(zero_end - (char*)deg), stream);

  // phase 1: histogram ∪ gemm1 ∪ cvt_w, role-striped 5:1
  mega1<<<7500, 256, 0, stream>>>(srcv, dstv, ea, deg, cnt, rank,
                                  x, W1, Acat, W2, W3, Wt2, Wt3);

  const int nb = (NN + 255) / 256;  // 196
  scan1<<<nb, 256, 0, stream>>>(cnt, deg, partial, bsum, NN);      // + dinv
  scan3<<<nb, 256, 0, stream>>>(partial, bsum, cnt, rowptr, edges, NN);  // + scan2 + pad
  scatter_kernel<<<(EE + 255) / 256, 256, 0, stream>>>(srcv, dstv, ea, deg, rowptr, rank,
                                                       edges, EE);

  const int PG = NN / 16;            // 3125 prop blocks (4 waves x 4 nodes each)
  const int GX = (NN + 255) / 256;   // gemm row-blocks

  ushort* A0 = Acat + 0 * 64;  ushort* A1 = Acat + 1 * 64;  ushort* A2 = Acat + 2 * 64;
  ushort* A3 = Acat + 3 * 64;  ushort* A4 = Acat + 4 * 64;
  ushort* B0 = Bcat + 0 * 64;  ushort* B1 = Bcat + 1 * 64;  ushort* B2 = Bcat + 2 * 64;
  ushort* B3 = Bcat + 3 * 64;  ushort* B4 = Bcat + 4 * 64;
  const int S = 320;

  // ---- Layer 1 (Clenshaw), a_k already in Acat from mega1 ----
  prop_kernel<1, false><<<PG, 256, 0, stream>>>(rowptr, edges, A4, S, A3, S, 1.f,
      nullptr, 0, 0.f, nullptr, A3, S, NN, 2.f);
  prop_kernel<2, false><<<PG, 256, 0, stream>>>(rowptr, edges, A3, S, A2, S, 1.f,
      A4, S, -1.f, nullptr, A2, S, NN, 2.f);
  prop_kernel<2, false><<<PG, 256, 0, stream>>>(rowptr, edges, A2, S, A1, S, 1.f,
      A3, S, -1.f, nullptr, A1, S, NN, 2.f);
  prop_kernel<2, true><<<PG, 256, 0, stream>>>(rowptr, edges, A1, S, A0, S, 1.f,
      A2, S, -1.f, lb1, h1, 64, NN, 1.f);

  // ---- Layer 2 (Clenshaw): a_k = h1 @ W2_k -> Bcat ----
  gemm_mfma<64, 320, false><<<dim3(GX, 5), 256, 0, stream>>>(h1, Wt2, nullptr, Bcat, NN);
  prop_kernel<1, false><<<PG, 256, 0, stream>>>(rowptr, edges, B4, S, B3, S, 1.f,
      nullptr, 0, 0.f, nullptr, B3, S, NN, 2.f);
  prop_kernel<2, false><<<PG, 256, 0, stream>>>(rowptr, edges, B3, S, B2, S, 1.f,
      B4, S, -1.f, nullptr, B2, S, NN, 2.f);
  prop_kernel<2, false><<<PG, 256, 0, stream>>>(rowptr, edges, B2, S, B1, S, 1.f,
      B3, S, -1.f, nullptr, B1, S, NN, 2.f);
  // h2 -> Acat block 0 (Tx0), strided
  prop_kernel<2, true><<<PG, 256, 0, stream>>>(rowptr, edges, B1, S, B0, S, 1.f,
      B2, S, -1.f, lb2, A0, S, NN, 1.f);

  // ---- Layer 3 (forward recursion, Tx_k in Acat blocks) ----
  prop_kernel<0, false><<<PG, 256, 0, stream>>>(rowptr, edges, A0, S, nullptr, 0, 0.f,
      nullptr, 0, 0.f, nullptr, A1, S, NN, 1.f);
  prop_kernel<1, false><<<PG, 256, 0, stream>>>(rowptr, edges, A1, S, A0, S, -1.f,
      nullptr, 0, 0.f, nullptr, A2, S, NN, 2.f);
  prop_kernel<1, false><<<PG, 256, 0, stream>>>(rowptr, edges, A2, S, A1, S, -1.f,
      nullptr, 0, 0.f, nullptr, A3, S, NN, 2.f);
  prop_kernel<1, false><<<PG, 256, 0, stream>>>(rowptr, edges, A3, S, A2, S, -1.f,
      nullptr, 0, 0.f, nullptr, A4, S, NN, 2.f);
  // h3 = relu([Tx0|..|Tx4] @ W3stack + b3)
  gemm_mfma<320, 128, true><<<dim3(GX, 2), 256, 0, stream>>>(Acat, Wt3, lb3, h3, NN);

  // ---- pool + head ----
  pool_kernel<<<(NN + 63) / 64, 128, 0, stream>>>(h3, batch, pooled, gcnt, NN);
  head_kernel<<<GG, 128, 0, stream>>>(pooled, gcnt, Wl, bl, (float*)d_out);
}

// Round 15
// 566.605 us; speedup vs baseline: 12.4171x; 1.0454x over previous
//
#include <hip/hip_runtime.h>
#include <hip/hip_bf16.h>
#include <hip/hip_fp16.h>

#define NN 50000
#define EE 1600000
#define GG 500

#define GX1 196          // gemm row-blocks = ceil(NN/256)
#define GB1 (GX1 * 5)    // gemm1 blocks (5 column tiles of 64)
#define CVB 240          // cvt_w blocks (61440 elems / 256)
// mega1: 7500 blocks in 1250 groups of 6 -> 5 hist + 1 rider

typedef __bf16 bf16x8 __attribute__((ext_vector_type(8)));
typedef float  f32x4  __attribute__((ext_vector_type(4)));

__device__ __forceinline__ float b2f(ushort u) {
  return __uint_as_float(((unsigned)u) << 16);
}
__device__ __forceinline__ ushort f2b(float f) {
  unsigned u = __float_as_uint(f);
  unsigned r = (u + 0x7fff + ((u >> 16) & 1)) >> 16;   // RNE
  return (ushort)r;
}
__device__ __forceinline__ float lo16(uint v) { return __uint_as_float(v << 16); }
__device__ __forceinline__ float hi16(uint v) { return __uint_as_float(v & 0xffff0000u); }
__device__ __forceinline__ float h2f(uint hb) {
  __half h; ushort s = (ushort)hb;
  __builtin_memcpy(&h, &s, 2);
  return __half2float(h);
}

// Edge meta: one u32 per edge = {src:u16 | fp16(w):u16}.

// ---------------- mega phase 1: hist ∪ gemm1 ∪ cvt_w, role-STRIPED ----------------

__global__ __launch_bounds__(256) void mega1(
    const int* __restrict__ src, const int* __restrict__ dst,
    const float* __restrict__ ea, float* __restrict__ deg,
    int* __restrict__ cnt, int* __restrict__ rank,
    const float* __restrict__ x, const float* __restrict__ W1,
    ushort* __restrict__ Acat,
    const float* __restrict__ W2, const float* __restrict__ W3,
    ushort* __restrict__ Wt2, ushort* __restrict__ Wt3)
{
  const int r = blockIdx.x % 6;
  const int gq = blockIdx.x / 6;      // 0..1249
  if (r < 5) {
    int i = (gq * 5 + r) * 256 + threadIdx.x;
    if (i < EE) {
      atomicAdd(&deg[src[i]], ea[i]);
      rank[i] = atomicAdd(&cnt[dst[i]], 1);
    }
    return;
  }
  if (gq < GB1) {
    const int bx = gq % GX1, by = gq / GX1;
    const int lane = threadIdx.x & 63;
    const int wid  = threadIdx.x >> 6;
    const int rb = bx * 256;
    const int cb = by * 64;
    const int lr = lane & 15;
    const int lk = (lane >> 4) << 3;
    f32x4 acc[4][4] = {};
    for (int kc = 0; kc < 128; kc += 64) {
      bf16x8 bfrag[2][4];
      #pragma unroll
      for (int ks = 0; ks < 2; ++ks)
        #pragma unroll
        for (int nt = 0; nt < 4; ++nt) {
          int col = cb + nt * 16 + lr;        // 0..319
          int kk  = kc + ks * 32 + lk;
          const float* wp = &W1[((size_t)(col >> 6) * 128 + kk) * 64 + (col & 63)];
          union { bf16x8 v; ushort u[8]; } bu;
          #pragma unroll
          for (int t = 0; t < 8; ++t) bu.u[t] = f2b(wp[t * 64]);
          bfrag[ks][nt] = bu.v;
        }
      #pragma unroll
      for (int s = 0; s < 4; ++s) {
        const int row = rb + (wid * 4 + s) * 16 + lr;
        #pragma unroll
        for (int ks = 0; ks < 2; ++ks) {
          union { bf16x8 v; ushort u[8]; } au;
          if (row < NN) {
            const float* ap = &x[(size_t)row * 128 + kc + ks * 32 + lk];
            float4 f0 = *(const float4*)ap;
            float4 f1 = *(const float4*)(ap + 4);
            au.u[0] = f2b(f0.x); au.u[1] = f2b(f0.y);
            au.u[2] = f2b(f0.z); au.u[3] = f2b(f0.w);
            au.u[4] = f2b(f1.x); au.u[5] = f2b(f1.y);
            au.u[6] = f2b(f1.z); au.u[7] = f2b(f1.w);
          } else {
            au.v = bf16x8{};
          }
          #pragma unroll
          for (int nt = 0; nt < 4; ++nt)
            acc[s][nt] = __builtin_amdgcn_mfma_f32_16x16x32_bf16(au.v, bfrag[ks][nt],
                                                                 acc[s][nt], 0, 0, 0);
        }
      }
    }
    #pragma unroll
    for (int s = 0; s < 4; ++s)
      #pragma unroll
      for (int nt = 0; nt < 4; ++nt) {
        const int col = cb + nt * 16 + lr;
        #pragma unroll
        for (int rr = 0; rr < 4; ++rr) {
          const int row = rb + (wid * 4 + s) * 16 + ((lane >> 4) << 2) + rr;
          if (row < NN) Acat[(size_t)row * 320 + col] = f2b(acc[s][nt][rr]);
        }
      }
    return;
  }
  if (gq < GB1 + CVB) {
    int t = (gq - GB1) * 256 + threadIdx.x;      // 0..61439
    if (t < 320 * 64) {
      int j = t / 64, k = t % 64;
      Wt2[t] = f2b(W2[((size_t)(j >> 6) * 64 + k) * 64 + (j & 63)]);
    } else {
      int t2 = t - 320 * 64;            // < 128*320
      int j = t2 / 320, k = t2 % 320;
      Wt3[t2] = f2b(W3[(size_t)k * 128 + j]);
    }
  }
}

// ---------------- scans (4-padded counts) + fused dinv / pad ----------------

__global__ void scan1(const int* __restrict__ cnt, float* __restrict__ deg,
                      int* __restrict__ partial, int* __restrict__ bsum, int n) {
  __shared__ int s[256];
  int t = threadIdx.x, i = blockIdx.x * 256 + t;
  if (i < n) { float d = deg[i]; deg[i] = (d > 0.f) ? (1.0f / sqrtf(d)) : 0.f; }
  int v = (i < n) ? ((cnt[i] + 3) & ~3) : 0;
  s[t] = v; __syncthreads();
  for (int off = 1; off < 256; off <<= 1) {
    int xv = (t >= off) ? s[t - off] : 0;
    __syncthreads(); s[t] += xv; __syncthreads();
  }
  if (i < n) partial[i] = s[t];
  if (t == 255) bsum[blockIdx.x] = s[255];
}

// scan3 absorbs scan2: each block reduces bsum[0..blockIdx-1] in LDS.
__global__ void scan3(const int* __restrict__ partial, const int* __restrict__ bsum,
                      const int* __restrict__ cnt, int* __restrict__ rowptr,
                      uint* __restrict__ edges, int n) {
  __shared__ int soff[256];
  int t = threadIdx.x;
  soff[t] = (t < (int)blockIdx.x) ? bsum[t] : 0;   // blockIdx < 196 <= 256
  __syncthreads();
  for (int off = 128; off > 0; off >>= 1) {
    if (t < off) soff[t] += soff[t + off];
    __syncthreads();
  }
  const int off0 = soff[0];
  int i = blockIdx.x * 256 + t;
  if (i < n) {
    int end = partial[i] + off0;          // padded end of row i
    rowptr[i + 1] = end;
    if (i == 0) rowptr[0] = 0;
    int c = cnt[i];
    int start = end - ((c + 3) & ~3);
    for (int q = start + c; q < end; ++q) edges[q] = 0u;  // {src=0, w=+0.0h}
  }
}

// atomic-free scatter: pos = rowptr[d] + rank; meta packed {src:u16 | fp16 w}
__global__ void scatter_kernel(const int* __restrict__ src, const int* __restrict__ dst,
                               const float* __restrict__ ea, const float* __restrict__ dinv,
                               const int* __restrict__ rowptr, const int* __restrict__ rank,
                               uint* __restrict__ edges, int e) {
  int i = blockIdx.x * blockDim.x + threadIdx.x;
  if (i < e) {
    int s = src[i], d = dst[i];
    float w = -dinv[s] * ea[i] * dinv[d];
    __half h = __float2half_rn(w);
    ushort hb; __builtin_memcpy(&hb, &h, 2);
    edges[rowptr[d] + rank[i]] = (uint)(unsigned short)s | ((uint)hb << 16);
  }
}

// ---------------- sparse propagation V5b: 4 node-chains per wave, 4B meta ----
// Wave handles 4 consecutive nodes (quarter-wave each): q=lane>>4 node,
// grp=(lane>>3)&1 edge slot, sub=lane&7 the 16B row chunk. One gather
// instruction covers 8 edges x 128B; 4 chains x2 unroll = 8 outstanding
// gathers per wave. Rows padded to %4 with 0-meta fillers.
// out = alpha * prop(g) + c1*a1 + c2*a2   [+ bias, relu]

template<int NADD, bool RELUB>
__global__ __launch_bounds__(256) void prop_kernel(
    const int* __restrict__ rowptr, const uint* __restrict__ edges,
    const ushort* __restrict__ g, int sg,
    const ushort* __restrict__ a1, int sa1, float c1,
    const ushort* __restrict__ a2, int sa2, float c2,
    const float* __restrict__ bias,
    ushort* __restrict__ out, int so, int n, float alpha)
{
  const int wave = threadIdx.x >> 6;
  const int lane = threadIdx.x & 63;
  const int q    = lane >> 4;        // node chain 0..3
  const int grp  = (lane >> 3) & 1;  // edge slot within pair
  const int sub  = lane & 7;         // 16B chunk of 128B row
  const int nd = (blockIdx.x * 4 + wave) * 4 + q;   // grid covers n exactly
  const int e0 = rowptr[nd];
  const int e1 = rowptr[nd + 1];

  float ra[8] = {}, rb[8] = {};
  int j = e0 + grp;                  // this lane's edge stream: stride 2
  for (; j + 2 < e1; j += 4) {       // unroll 2 (rows padded %4 -> no tail)
    uint p0 = edges[j];
    uint p1 = edges[j + 2];
    uint4 v0 = *(const uint4*)&g[(size_t)(p0 & 0xffffu) * sg + sub * 8];
    uint4 v1 = *(const uint4*)&g[(size_t)(p1 & 0xffffu) * sg + sub * 8];
    float w0 = h2f(p0 >> 16);
    float w1 = h2f(p1 >> 16);
    ra[0] += w0 * lo16(v0.x); ra[1] += w0 * hi16(v0.x);
    ra[2] += w0 * lo16(v0.y); ra[3] += w0 * hi16(v0.y);
    ra[4] += w0 * lo16(v0.z); ra[5] += w0 * hi16(v0.z);
    ra[6] += w0 * lo16(v0.w); ra[7] += w0 * hi16(v0.w);
    rb[0] += w1 * lo16(v1.x); rb[1] += w1 * hi16(v1.x);
    rb[2] += w1 * lo16(v1.y); rb[3] += w1 * hi16(v1.y);
    rb[4] += w1 * lo16(v1.z); rb[5] += w1 * hi16(v1.z);
    rb[6] += w1 * lo16(v1.w); rb[7] += w1 * hi16(v1.w);
  }
  float r[8];
  #pragma unroll
  for (int e = 0; e < 8; ++e) {
    float t = ra[e] + rb[e];
    t += __shfl_xor(t, 8, 64);       // combine the two edge slots (within quarter)
    r[e] = alpha * t;
  }
  if constexpr (NADD >= 1) {
    uint4 u = *(const uint4*)&a1[(size_t)nd * sa1 + sub * 8];
    r[0] += c1 * lo16(u.x); r[1] += c1 * hi16(u.x);
    r[2] += c1 * lo16(u.y); r[3] += c1 * hi16(u.y);
    r[4] += c1 * lo16(u.z); r[5] += c1 * hi16(u.z);
    r[6] += c1 * lo16(u.w); r[7] += c1 * hi16(u.w);
  }
  if constexpr (NADD >= 2) {
    uint4 u = *(const uint4*)&a2[(size_t)nd * sa2 + sub * 8];
    r[0] += c2 * lo16(u.x); r[1] += c2 * hi16(u.x);
    r[2] += c2 * lo16(u.y); r[3] += c2 * hi16(u.y);
    r[4] += c2 * lo16(u.z); r[5] += c2 * hi16(u.z);
    r[6] += c2 * lo16(u.w); r[7] += c2 * hi16(u.w);
  }
  if constexpr (RELUB) {
    float4 b0 = *(const float4*)&bias[sub * 8];
    float4 b1 = *(const float4*)&bias[sub * 8 + 4];
    r[0] = fmaxf(r[0] + b0.x, 0.f); r[1] = fmaxf(r[1] + b0.y, 0.f);
    r[2] = fmaxf(r[2] + b0.z, 0.f); r[3] = fmaxf(r[3] + b0.w, 0.f);
    r[4] = fmaxf(r[4] + b1.x, 0.f); r[5] = fmaxf(r[5] + b1.y, 0.f);
    r[6] = fmaxf(r[6] + b1.z, 0.f); r[7] = fmaxf(r[7] + b1.w, 0.f);
  }
  if (grp == 0) {                    // 8 lanes per quarter write the 128B row
    uint4 o;
    o.x = (uint)f2b(r[0]) | ((uint)f2b(r[1]) << 16);
    o.y = (uint)f2b(r[2]) | ((uint)f2b(r[3]) << 16);
    o.z = (uint)f2b(r[4]) | ((uint)f2b(r[5]) << 16);
    o.w = (uint)f2b(r[6]) | ((uint)f2b(r[7]) << 16);
    *(uint4*)&out[(size_t)nd * so + sub * 8] = o;
  }
}

// ---------------- MFMA GEMM (bf16 in, bf16 out) ----------------

template<int Ci, int Co, bool BR>
__global__ __launch_bounds__(256) void gemm_mfma(const ushort* __restrict__ A,
    const ushort* __restrict__ Wt, const float* __restrict__ bias,
    ushort* __restrict__ C, int n)
{
  const int lane = threadIdx.x & 63;
  const int wid  = threadIdx.x >> 6;
  const int rb = blockIdx.x * 256;
  const int cb = blockIdx.y * 64;
  const int lr = lane & 15;
  const int lk = (lane >> 4) << 3;
  f32x4 acc[4][4] = {};

  for (int kc = 0; kc < Ci; kc += 64) {
    bf16x8 bfrag[2][4];
    #pragma unroll
    for (int ks = 0; ks < 2; ++ks)
      #pragma unroll
      for (int nt = 0; nt < 4; ++nt)
        bfrag[ks][nt] = *(const bf16x8*)&Wt[(size_t)(cb + nt * 16 + lr) * Ci + kc + ks * 32 + lk];
    #pragma unroll
    for (int s = 0; s < 4; ++s) {
      const int row = rb + (wid * 4 + s) * 16 + lr;
      const ushort* ap = &A[(size_t)row * Ci + kc + lk];
      #pragma unroll
      for (int ks = 0; ks < 2; ++ks) {
        bf16x8 af = {};
        if (row < n) af = *(const bf16x8*)(ap + ks * 32);
        #pragma unroll
        for (int nt = 0; nt < 4; ++nt)
          acc[s][nt] = __builtin_amdgcn_mfma_f32_16x16x32_bf16(af, bfrag[ks][nt], acc[s][nt], 0, 0, 0);
      }
    }
  }

  #pragma unroll
  for (int s = 0; s < 4; ++s)
    #pragma unroll
    for (int nt = 0; nt < 4; ++nt) {
      const int col = cb + nt * 16 + lr;
      #pragma unroll
      for (int r = 0; r < 4; ++r) {
        const int row = rb + (wid * 4 + s) * 16 + ((lane >> 4) << 2) + r;
        if (row < n) {
          float v = acc[s][nt][r];
          if constexpr (BR) v = fmaxf(v + bias[col], 0.f);
          C[(size_t)row * Co + col] = f2b(v);
        }
      }
    }
}

// ---------------- pooling + head ----------------

__global__ __launch_bounds__(128) void pool_kernel(const ushort* __restrict__ h,
    const int* __restrict__ batch, float* __restrict__ pooled,
    float* __restrict__ gcnt, int n) {
  const int f = threadIdx.x;
  const int i0 = blockIdx.x * 64;
  const int iend = min(i0 + 64, n);
  int cur = batch[i0];
  float acc = 0.f;
  int run = 0;
  for (int i = i0; i < iend; ++i) {
    int b = batch[i];
    float v = b2f(h[(size_t)i * 128 + f]);
    if (b != cur) {
      atomicAdd(&pooled[cur * 128 + f], acc);
      if (f == 0) atomicAdd(&gcnt[cur], (float)run);
      acc = 0.f; run = 0; cur = b;
    }
    acc += v; run++;
  }
  atomicAdd(&pooled[cur * 128 + f], acc);
  if (f == 0) atomicAdd(&gcnt[cur], (float)run);
}

__global__ __launch_bounds__(128) void head_kernel(const float* __restrict__ pooled,
    const float* __restrict__ gcnt, const float* __restrict__ Wl,
    const float* __restrict__ bl, float* __restrict__ outp)
{
  int g = blockIdx.x, t = threadIdx.x;
  float denom = fmaxf(gcnt[g], 1.f);
  float p = pooled[g * 128 + t] / denom;
  __shared__ float s0[128], s1[128];
  s0[t] = p * Wl[t * 2 + 0];
  s1[t] = p * Wl[t * 2 + 1];
  __syncthreads();
  for (int off = 64; off > 0; off >>= 1) {
    if (t < off) { s0[t] += s0[t + off]; s1[t] += s1[t + off]; }
    __syncthreads();
  }
  if (t == 0) {
    float a = s0[0] + bl[0], b = s1[0] + bl[1];
    float m = fmaxf(a, b);
    float z = logf(expf(a - m) + expf(b - m)) + m;
    outp[g * 2 + 0] = a - z;
    outp[g * 2 + 1] = b - z;
  }
}

// ---------------- launch ----------------

extern "C" void kernel_launch(void* const* d_in, const int* in_sizes, int n_in,
                              void* d_out, int out_size, void* d_ws, size_t ws_size,
                              hipStream_t stream) {
  const float* x   = (const float*)d_in[0];
  const int*   ei  = (const int*)d_in[1];
  const float* ea  = (const float*)d_in[2];
  const int* batch = (const int*)d_in[3];
  const float* W1  = (const float*)d_in[4];
  const float* lb1 = (const float*)d_in[5];
  const float* W2  = (const float*)d_in[6];
  const float* lb2 = (const float*)d_in[7];
  const float* W3  = (const float*)d_in[8];
  const float* lb3 = (const float*)d_in[9];
  const float* Wl  = (const float*)d_in[10];
  const float* bl  = (const float*)d_in[11];
  const int* srcv = ei;
  const int* dstv = ei + EE;

  char* w = (char*)d_ws;
  auto alloc = [&](size_t bytes) -> char* {
    char* p = w; w += (bytes + 255) & ~(size_t)255; return p;
  };
  // zero-init region: deg, cnt, pooled+gcnt contiguous (one memset)
  float* deg    = (float*)alloc((size_t)NN * 4);          // becomes dinv in scan1
  int*   cnt    = (int*)alloc((size_t)NN * 4);
  float* pooled = (float*)alloc((size_t)(GG * 128 + GG) * 4);
  float* gcnt   = pooled + GG * 128;
  char*  zero_end = w;
  int*   rowptr = (int*)alloc((size_t)(NN + 1) * 4);
  int*   bsum   = (int*)alloc(256 * 4);
  int*   rank   = (int*)alloc((size_t)EE * 4);
  uint*  edges  = (uint*)alloc((size_t)(EE + 4 * NN) * 4); // rows padded to %4
  ushort* Acat  = (ushort*)alloc((size_t)NN * 320 * 2);   // a_k / Clenshaw / Tx_k
  ushort* Bcat  = (ushort*)alloc((size_t)NN * 320 * 2);   // layer2 blocks; later h3
  ushort* h1    = (ushort*)alloc((size_t)NN * 64 * 2);
  ushort* Wt2   = (ushort*)alloc((size_t)320 * 64 * 2);
  ushort* Wt3   = (ushort*)alloc((size_t)128 * 320 * 2);
  int*   partial = (int*)Bcat;     // scan scratch (Bcat unused until gemm2)
  ushort* h3 = Bcat;               // layer-3 output reuses Bcat

  hipMemsetAsync(deg, 0, (size_t)(zero_end - (char*)deg), stream);

  // phase 1: histogram ∪ gemm1 ∪ cvt_w, role-striped 5:1
  mega1<<<7500, 256, 0, stream>>>(srcv, dstv, ea, deg, cnt, rank,
                                  x, W1, Acat, W2, W3, Wt2, Wt3);

  const int nb = (NN + 255) / 256;  // 196
  scan1<<<nb, 256, 0, stream>>>(cnt, deg, partial, bsum, NN);      // + dinv
  scan3<<<nb, 256, 0, stream>>>(partial, bsum, cnt, rowptr, edges, NN);  // + scan2 + pad
  scatter_kernel<<<(EE + 255) / 256, 256, 0, stream>>>(srcv, dstv, ea, deg, rowptr, rank,
                                                       edges, EE);

  const int PG = NN / 16;            // 3125 prop blocks (4 waves x 4 nodes each)
  const int GX = (NN + 255) / 256;   // gemm row-blocks

  ushort* A0 = Acat + 0 * 64;  ushort* A1 = Acat + 1 * 64;  ushort* A2 = Acat + 2 * 64;
  ushort* A3 = Acat + 3 * 64;  ushort* A4 = Acat + 4 * 64;
  ushort* B0 = Bcat + 0 * 64;  ushort* B1 = Bcat + 1 * 64;  ushort* B2 = Bcat + 2 * 64;
  ushort* B3 = Bcat + 3 * 64;  ushort* B4 = Bcat + 4 * 64;
  const int S = 320;

  // ---- Layer 1 (Clenshaw), a_k already in Acat from mega1 ----
  prop_kernel<1, false><<<PG, 256, 0, stream>>>(rowptr, edges, A4, S, A3, S, 1.f,
      nullptr, 0, 0.f, nullptr, A3, S, NN, 2.f);
  prop_kernel<2, false><<<PG, 256, 0, stream>>>(rowptr, edges, A3, S, A2, S, 1.f,
      A4, S, -1.f, nullptr, A2, S, NN, 2.f);
  prop_kernel<2, false><<<PG, 256, 0, stream>>>(rowptr, edges, A2, S, A1, S, 1.f,
      A3, S, -1.f, nullptr, A1, S, NN, 2.f);
  prop_kernel<2, true><<<PG, 256, 0, stream>>>(rowptr, edges, A1, S, A0, S, 1.f,
      A2, S, -1.f, lb1, h1, 64, NN, 1.f);

  // ---- Layer 2 (Clenshaw): a_k = h1 @ W2_k -> Bcat ----
  gemm_mfma<64, 320, false><<<dim3(GX, 5), 256, 0, stream>>>(h1, Wt2, nullptr, Bcat, NN);
  prop_kernel<1, false><<<PG, 256, 0, stream>>>(rowptr, edges, B4, S, B3, S, 1.f,
      nullptr, 0, 0.f, nullptr, B3, S, NN, 2.f);
  prop_kernel<2, false><<<PG, 256, 0, stream>>>(rowptr, edges, B3, S, B2, S, 1.f,
      B4, S, -1.f, nullptr, B2, S, NN, 2.f);
  prop_kernel<2, false><<<PG, 256, 0, stream>>>(rowptr, edges, B2, S, B1, S, 1.f,
      B3, S, -1.f, nullptr, B1, S, NN, 2.f);
  // h2 -> Acat block 0 (Tx0), strided
  prop_kernel<2, true><<<PG, 256, 0, stream>>>(rowptr, edges, B1, S, B0, S, 1.f,
      B2, S, -1.f, lb2, A0, S, NN, 1.f);

  // ---- Layer 3 (forward recursion, Tx_k in Acat blocks) ----
  prop_kernel<0, false><<<PG, 256, 0, stream>>>(rowptr, edges, A0, S, nullptr, 0, 0.f,
      nullptr, 0, 0.f, nullptr, A1, S, NN, 1.f);
  prop_kernel<1, false><<<PG, 256, 0, stream>>>(rowptr, edges, A1, S, A0, S, -1.f,
      nullptr, 0, 0.f, nullptr, A2, S, NN, 2.f);
  prop_kernel<1, false><<<PG, 256, 0, stream>>>(rowptr, edges, A2, S, A1, S, -1.f,
      nullptr, 0, 0.f, nullptr, A3, S, NN, 2.f);
  prop_kernel<1, false><<<PG, 256, 0, stream>>>(rowptr, edges, A3, S, A2, S, -1.f,
      nullptr, 0, 0.f, nullptr, A4, S, NN, 2.f);
  // h3 = relu([Tx0|..|Tx4] @ W3stack + b3)
  gemm_mfma<320, 128, true><<<dim3(GX, 2), 256, 0, stream>>>(Acat, Wt3, lb3, h3, NN);

  // ---- pool + head ----
  pool_kernel<<<(NN + 63) / 64, 128, 0, stream>>>(h3, batch, pooled, gcnt, NN);
  head_kernel<<<GG, 128, 0, stream>>>(pooled, gcnt, Wl, bl, (float*)d_out);
}